// Round 10
// baseline (217.652 us; speedup 1.0000x reference)
//
#include <hip/hip_runtime.h>

#define L_SEQ 2048
#define D_DIM 768
#define N_ST 16
#define NB 4
#define NJ 33            // 16 B + 16 C + 1 s1 (logical)
#define BCS 48           // padded row stride (192 B -> float4 aligned)
#define NROWS (NB * L_SEQ)          // 8192
#define DN (D_DIM * N_ST)           // 12288

// proj GEMM tiling
#define DSPLIT 8
#define DSEG (D_DIM / DSPLIT)       // 96
#define DK 32
#define NCHUNK (DSEG / DK)          // 3
#define RB 128
#define XST 132
#define WST 64

typedef float v2f __attribute__((ext_vector_type(2)));

__device__ __forceinline__ float fast_exp2(float x) {
#if __has_builtin(__builtin_amdgcn_exp2f)
  return __builtin_amdgcn_exp2f(x);
#else
  return __expf(x * 0.69314718055994531f);
#endif
}

// softplus = log2(1+2^(v*log2e))*ln2; guard large v (exp2 -> inf)
__device__ __forceinline__ float softplus_f(float v) {
  float e = fast_exp2(v * 1.44269504088896f);
  float l = __log2f(1.0f + e) * 0.69314718055994531f;
  return (v > 15.0f) ? v : l;
}

// pw2[k] = {e1^(2k+1), e1^(2k+2)} via log-depth tree
__device__ __forceinline__ void pow_tree2(float e1, v2f pw2[8]) {
  float e2s = e1 * e1;
  float e4s = e2s * e2s;
  float e8s = e4s * e4s;
  v2f s2 = {e2s, e2s}, s4 = {e4s, e4s}, s8 = {e8s, e8s};
  pw2[0] = (v2f){e1, e2s};
  pw2[1] = pw2[0] * s2;
  pw2[2] = pw2[0] * s4;
  pw2[3] = pw2[1] * s4;
  pw2[4] = pw2[0] * s8;
  pw2[5] = pw2[1] * s8;
  pw2[6] = pw2[2] * s8;
  pw2[7] = pw2[3] * s8;
}

// ---------------------------------------------------------------------------
// Projection GEMM, K-split 8 ways, fused reduction: partial sums atomically
// accumulated into zero-initialized BC48; ds==0 block also adds the bias.
// ---------------------------------------------------------------------------
__global__ __launch_bounds__(256) void k_proj_gemm(
    const float* __restrict__ x, const float* __restrict__ W_bc,
    const float* __restrict__ W_1, const float* __restrict__ b_bc,
    const float* __restrict__ b_1, float* __restrict__ BC48) {
  __shared__ float xs_t[DK * XST];
  __shared__ float ws_t[DK * WST];

  const int ds  = blockIdx.x % DSPLIT;
  const int rb0 = (blockIdx.x / DSPLIT) * RB;
  const int dbase = ds * DSEG;
  const int tid = threadIdx.x;
  const int rg = tid & 31;
  const int jg = tid >> 5;

  float acc[4][5];
#pragma unroll
  for (int i = 0; i < 4; ++i)
#pragma unroll
    for (int k = 0; k < 5; ++k) acc[i][k] = 0.0f;

  const int lrow = tid >> 1;
  const int lhalf = (tid & 1) * 16;
  const float* xg_row = x + (size_t)(rb0 + lrow) * D_DIM + dbase + lhalf;

  for (int ch = 0; ch < NCHUNK; ++ch) {
    const int dc = dbase + ch * DK;
    float4 xv[4];
#pragma unroll
    for (int q = 0; q < 4; ++q)
      xv[q] = *(const float4*)(xg_row + ch * DK + q * 4);
    float wv[8];
    int widx[8];
#pragma unroll
    for (int u = 0; u < 8; ++u) {
      int idx = tid + u * 256;
      int dk = idx >> 6, slot = idx & 63;
      int wjg = slot >> 3, wk = slot & 7;
      int j = wjg + 8 * wk;
      float v = 0.0f;
      if (wk < 5) {
        if (j < 32)       v = W_bc[(size_t)j * D_DIM + dc + dk];
        else if (j == 32) v = W_1[dc + dk];
      }
      wv[u] = v; widx[u] = dk * WST + slot;
    }
    __syncthreads();
#pragma unroll
    for (int q = 0; q < 4; ++q) {
      xs_t[(lhalf + q * 4 + 0) * XST + lrow] = xv[q].x;
      xs_t[(lhalf + q * 4 + 1) * XST + lrow] = xv[q].y;
      xs_t[(lhalf + q * 4 + 2) * XST + lrow] = xv[q].z;
      xs_t[(lhalf + q * 4 + 3) * XST + lrow] = xv[q].w;
    }
#pragma unroll
    for (int u = 0; u < 8; ++u) ws_t[widx[u]] = wv[u];
    __syncthreads();
#pragma unroll 8
    for (int dk = 0; dk < DK; ++dk) {
      float4 xr = *(const float4*)&xs_t[dk * XST + rg * 4];
      float4 wr = *(const float4*)&ws_t[dk * WST + jg * 8];
      float w4  = ws_t[dk * WST + jg * 8 + 4];
      float xa[4] = {xr.x, xr.y, xr.z, xr.w};
      float wa[5] = {wr.x, wr.y, wr.z, wr.w, w4};
#pragma unroll
      for (int i = 0; i < 4; ++i)
#pragma unroll
        for (int k = 0; k < 5; ++k)
          acc[i][k] = fmaf(xa[i], wa[k], acc[i][k]);
    }
  }

#pragma unroll
  for (int i = 0; i < 4; ++i) {
    int row = rb0 + rg * 4 + i;
#pragma unroll
    for (int k = 0; k < 5; ++k) {
      int j = jg + 8 * k;
      if (k < 4 || jg == 0) {
        float v = acc[i][k];
        if (ds == 0) v += (j < 32) ? b_bc[j] : b_1[0];
        atomicAdd(&BC48[(size_t)row * BCS + j], v);
      }
    }
  }
}

// ---------------------------------------------------------------------------
// Pass 1: per-chunk local scan, h0=0. Emits y_local -> out, chunk-end state H
// and delta-sum DS. Geometric-A fast path: dA_n = e1^(n+1).
// ---------------------------------------------------------------------------
template <int LC>
__global__ __launch_bounds__(256, 6) void k_scan1(
    const float* __restrict__ x, const float* __restrict__ A_log,
    const float* __restrict__ W_d, const float* __restrict__ b_d,
    const float* __restrict__ BC48, float* __restrict__ DS,
    float* __restrict__ H, float* __restrict__ out, int NC) {
  const int cb = blockIdx.x % 3;
  const int c  = (blockIdx.x / 3) % NC;
  const int b  = blockIdx.x / (3 * NC);
  const int d  = cb * 256 + threadIdx.x;

  const float wd = W_d[d], bd = b_d[d];
  float Aln[N_ST];
  {
    const float4* al4 = (const float4*)(A_log + (size_t)d * N_ST);
#pragma unroll
    for (int q = 0; q < 4; ++q) {
      float4 v = al4[q];
      Aln[4*q+0] = -__expf(v.x) * 1.44269504088896f;
      Aln[4*q+1] = -__expf(v.y) * 1.44269504088896f;
      Aln[4*q+2] = -__expf(v.z) * 1.44269504088896f;
      Aln[4*q+3] = -__expf(v.w) * 1.44269504088896f;
    }
  }
  bool geom = true;
#pragma unroll
  for (int n = 1; n < N_ST; ++n) {
    float ref = (float)(n + 1) * Aln[0];
    geom = geom && (fabsf(Aln[n] - ref) <= 1e-4f * fabsf(ref) + 1e-12f);
  }
  const float a0 = Aln[0];

  v2f h2[8];
#pragma unroll
  for (int k = 0; k < 8; ++k) h2[k] = (v2f){0.0f, 0.0f};
  float dsum = 0.0f;

  const int l0 = c * LC;
  const float* bc = BC48 + (size_t)(b * L_SEQ + l0) * BCS;
  const float* xp = x + (size_t)(b * L_SEQ + l0) * D_DIM + d;
  float* op = out + (size_t)(b * L_SEQ + l0) * D_DIM + d;

  if (geom) {
#pragma unroll 8
    for (int l = 0; l < LC; ++l) {
      const float* r = bc + l * BCS;
      float4 B0 = *(const float4*)(r + 0);
      float4 B1 = *(const float4*)(r + 4);
      float4 B2 = *(const float4*)(r + 8);
      float4 B3 = *(const float4*)(r + 12);
      float4 C0 = *(const float4*)(r + 16);
      float4 C1 = *(const float4*)(r + 20);
      float4 C2 = *(const float4*)(r + 24);
      float4 C3 = *(const float4*)(r + 28);
      float s1 = r[32];
      float delta = softplus_f(fmaf(s1, wd, bd));
      float xv = xp[(size_t)l * D_DIM];
      float f = delta * xv;
      dsum += delta;
      v2f pw2[8];
      pow_tree2(fast_exp2(a0 * delta), pw2);
      v2f f2 = {f, f};
      v2f y2 = {0.0f, 0.0f};
      h2[0] = pw2[0] * h2[0] + f2 * (v2f){B0.x, B0.y};  y2 += h2[0] * (v2f){C0.x, C0.y};
      h2[1] = pw2[1] * h2[1] + f2 * (v2f){B0.z, B0.w};  y2 += h2[1] * (v2f){C0.z, C0.w};
      h2[2] = pw2[2] * h2[2] + f2 * (v2f){B1.x, B1.y};  y2 += h2[2] * (v2f){C1.x, C1.y};
      h2[3] = pw2[3] * h2[3] + f2 * (v2f){B1.z, B1.w};  y2 += h2[3] * (v2f){C1.z, C1.w};
      h2[4] = pw2[4] * h2[4] + f2 * (v2f){B2.x, B2.y};  y2 += h2[4] * (v2f){C2.x, C2.y};
      h2[5] = pw2[5] * h2[5] + f2 * (v2f){B2.z, B2.w};  y2 += h2[5] * (v2f){C2.z, C2.w};
      h2[6] = pw2[6] * h2[6] + f2 * (v2f){B3.x, B3.y};  y2 += h2[6] * (v2f){C3.x, C3.y};
      h2[7] = pw2[7] * h2[7] + f2 * (v2f){B3.z, B3.w};  y2 += h2[7] * (v2f){C3.z, C3.w};
      op[(size_t)l * D_DIM] = y2.x + y2.y;
    }
  } else {
#pragma unroll 4
    for (int l = 0; l < LC; ++l) {
      const float* r = bc + l * BCS;
      float s1 = r[32];
      float delta = softplus_f(fmaf(s1, wd, bd));
      float f = delta * xp[(size_t)l * D_DIM];
      dsum += delta;
      float y = 0.0f;
#pragma unroll
      for (int k = 0; k < 8; ++k) {
        h2[k].x = fmaf(fast_exp2(delta * Aln[2*k]),   h2[k].x, f * r[2*k]);
        h2[k].y = fmaf(fast_exp2(delta * Aln[2*k+1]), h2[k].y, f * r[2*k+1]);
        y = fmaf(h2[k].x, r[16 + 2*k], y);
        y = fmaf(h2[k].y, r[16 + 2*k + 1], y);
      }
      op[(size_t)l * D_DIM] = y;
    }
  }

  DS[((size_t)b * NC + c) * D_DIM + d] = dsum;
  size_t base = ((size_t)(b * NC + c) * D_DIM + d) * N_ST;
  float4* H4 = (float4*)(H + base);
#pragma unroll
  for (int q = 0; q < 4; ++q)
    H4[q] = make_float4(h2[2*q].x, h2[2*q].y, h2[2*q+1].x, h2[2*q+1].y);
}

// ---------------------------------------------------------------------------
// Pass 2: inter-chunk combine, in-place, 8-deep prefetch. NC multiple of 8.
// ---------------------------------------------------------------------------
__global__ __launch_bounds__(256) void k_combine(
    const float* __restrict__ A_log, const float* __restrict__ DS,
    float* __restrict__ H, int NC) {
  const int b  = blockIdx.x / 48;
  const int tl = (blockIdx.x % 48) * 256 + threadIdx.x;   // 0..12287
  const int d = tl >> 4, n = tl & 15;
  const float Aln1 = -__expf(A_log[d * N_ST + n]) * 1.44269504088896f;
  const float* dsp = DS + (size_t)b * NC * D_DIM + d;
  float* Hp = H + (size_t)b * NC * DN + tl;

  float h = 0.0f;
  float pds[8], ph[8];
#pragma unroll
  for (int k = 0; k < 8; ++k) {
    pds[k] = dsp[(size_t)k * D_DIM];
    ph[k]  = Hp[(size_t)k * DN];
  }
  for (int g = 0; g < NC; g += 8) {
    float nds[8], nh[8];
    if (g + 8 < NC) {
#pragma unroll
      for (int k = 0; k < 8; ++k) {
        nds[k] = dsp[(size_t)(g + 8 + k) * D_DIM];
        nh[k]  = Hp[(size_t)(g + 8 + k) * DN];
      }
    }
#pragma unroll
    for (int k = 0; k < 8; ++k) {
      float p = fast_exp2(Aln1 * pds[k]);
      Hp[(size_t)(g + k) * DN] = h;                 // incoming state
      h = fmaf(p, h, ph[k]);
    }
#pragma unroll
    for (int k = 0; k < 8; ++k) { pds[k] = nds[k]; ph[k] = nh[k]; }
  }
}

// ---------------------------------------------------------------------------
// Pass 3: correction only. out[l] += sum_n exp(A_n * S_l) * h_in_n * C_l,n.
// Grid excludes c == 0 (already exact). No x read, no h recurrence.
// ---------------------------------------------------------------------------
template <int LC>
__global__ __launch_bounds__(256, 6) void k_scan2(
    const float* __restrict__ A_log, const float* __restrict__ W_d,
    const float* __restrict__ b_d, const float* __restrict__ BC48,
    const float* __restrict__ HIN, float* __restrict__ out, int NC) {
  const int cb  = blockIdx.x % 3;
  const int idx = blockIdx.x / 3;          // 0 .. NB*(NC-1)-1
  const int c   = idx % (NC - 1) + 1;      // chunks 1..NC-1
  const int b   = idx / (NC - 1);
  const int d   = cb * 256 + threadIdx.x;

  const float wd = W_d[d], bd = b_d[d];
  float Aln[N_ST];
  {
    const float4* al4 = (const float4*)(A_log + (size_t)d * N_ST);
#pragma unroll
    for (int q = 0; q < 4; ++q) {
      float4 v = al4[q];
      Aln[4*q+0] = -__expf(v.x) * 1.44269504088896f;
      Aln[4*q+1] = -__expf(v.y) * 1.44269504088896f;
      Aln[4*q+2] = -__expf(v.z) * 1.44269504088896f;
      Aln[4*q+3] = -__expf(v.w) * 1.44269504088896f;
    }
  }
  bool geom = true;
#pragma unroll
  for (int n = 1; n < N_ST; ++n) {
    float ref = (float)(n + 1) * Aln[0];
    geom = geom && (fabsf(Aln[n] - ref) <= 1e-4f * fabsf(ref) + 1e-12f);
  }
  const float a0 = Aln[0];

  v2f hin2[8];
  {
    size_t base = ((size_t)(b * NC + c) * D_DIM + d) * N_ST;
    const float4* HIN4 = (const float4*)(HIN + base);
#pragma unroll
    for (int q = 0; q < 4; ++q) {
      float4 v = HIN4[q];
      hin2[2*q]   = (v2f){v.x, v.y};
      hin2[2*q+1] = (v2f){v.z, v.w};
    }
  }

  const int l0 = c * LC;
  const float* bc = BC48 + (size_t)(b * L_SEQ + l0) * BCS;
  float* op = out + (size_t)(b * L_SEQ + l0) * D_DIM + d;

  if (geom) {
    float S = 0.0f;
#pragma unroll 8
    for (int l = 0; l < LC; ++l) {
      const float* r = bc + l * BCS;
      float yl = op[(size_t)l * D_DIM];            // y_local from pass 1
      float4 C0 = *(const float4*)(r + 16);
      float4 C1 = *(const float4*)(r + 20);
      float4 C2 = *(const float4*)(r + 24);
      float4 C3 = *(const float4*)(r + 28);
      float s1 = r[32];
      float delta = softplus_f(fmaf(s1, wd, bd));
      S += delta;
      v2f pw2[8];
      pow_tree2(fast_exp2(a0 * S), pw2);
      v2f acc = {0.0f, 0.0f};
      acc += pw2[0] * (hin2[0] * (v2f){C0.x, C0.y});
      acc += pw2[1] * (hin2[1] * (v2f){C0.z, C0.w});
      acc += pw2[2] * (hin2[2] * (v2f){C1.x, C1.y});
      acc += pw2[3] * (hin2[3] * (v2f){C1.z, C1.w});
      acc += pw2[4] * (hin2[4] * (v2f){C2.x, C2.y});
      acc += pw2[5] * (hin2[5] * (v2f){C2.z, C2.w});
      acc += pw2[6] * (hin2[6] * (v2f){C3.x, C3.y});
      acc += pw2[7] * (hin2[7] * (v2f){C3.z, C3.w});
      op[(size_t)l * D_DIM] = yl + acc.x + acc.y;
    }
  } else {
    float S = 0.0f;
#pragma unroll 4
    for (int l = 0; l < LC; ++l) {
      const float* r = bc + l * BCS;
      float yl = op[(size_t)l * D_DIM];
      float s1 = r[32];
      float delta = softplus_f(fmaf(s1, wd, bd));
      S += delta;
      float corr = 0.0f;
#pragma unroll
      for (int k = 0; k < 8; ++k) {
        corr = fmaf(fast_exp2(Aln[2*k]   * S) * hin2[k].x, r[16 + 2*k],     corr);
        corr = fmaf(fast_exp2(Aln[2*k+1] * S) * hin2[k].y, r[16 + 2*k + 1], corr);
      }
      op[(size_t)l * D_DIM] = yl + corr;
    }
  }
}

// ---------------------------------------------------------------------------
extern "C" void kernel_launch(void* const* d_in, const int* in_sizes, int n_in,
                              void* d_out, int out_size, void* d_ws, size_t ws_size,
                              hipStream_t stream) {
  const float* x     = (const float*)d_in[0];
  const float* A_log = (const float*)d_in[1];
  const float* W_bc  = (const float*)d_in[2];
  const float* b_bc  = (const float*)d_in[3];
  const float* W_1   = (const float*)d_in[4];
  const float* b_1   = (const float*)d_in[5];
  const float* W_d   = (const float*)d_in[6];
  const float* b_d   = (const float*)d_in[7];
  float* out = (float*)d_out;
  float* ws  = (float*)d_ws;

  // ws (floats): BC48 393216 + DS 3072*NC + H 49152*NC
  int NC = 64;
  {
    size_t need = ((size_t)NROWS * BCS + (3072ull + 49152ull) * 64) * 4ull;
    if (ws_size < need) NC = 32;
  }

  float* BC48 = ws;
  float* DSb  = ws + (size_t)NROWS * BCS;
  float* H    = DSb + (size_t)3072 * NC;

  hipMemsetAsync(BC48, 0, (size_t)NROWS * BCS * sizeof(float), stream);
  k_proj_gemm<<<(NROWS / RB) * DSPLIT, 256, 0, stream>>>(
      x, W_bc, W_1, b_bc, b_1, BC48);

  const int gs1 = 3 * NB * NC;
  const int gs2 = 3 * NB * (NC - 1);
  if (NC == 64) {
    k_scan1<32><<<gs1, 256, 0, stream>>>(x, A_log, W_d, b_d, BC48, DSb, H, out, NC);
    k_combine<<<192, 256, 0, stream>>>(A_log, DSb, H, NC);
    k_scan2<32><<<gs2, 256, 0, stream>>>(A_log, W_d, b_d, BC48, H, out, NC);
  } else {
    k_scan1<64><<<gs1, 256, 0, stream>>>(x, A_log, W_d, b_d, BC48, DSb, H, out, NC);
    k_combine<<<192, 256, 0, stream>>>(A_log, DSb, H, NC);
    k_scan2<64><<<gs2, 256, 0, stream>>>(A_log, W_d, b_d, BC48, H, out, NC);
  }
}

// Round 11
// 156.713 us; speedup vs baseline: 1.3889x; 1.3889x over previous
//
#include <hip/hip_runtime.h>

#define L_SEQ 2048
#define D_DIM 768
#define N_ST 16
#define NB 4
#define NJ 33            // 16 B + 16 C + 1 s1 (logical)
#define BCS 48           // padded row stride (192 B -> float4 aligned)
#define NROWS (NB * L_SEQ)          // 8192
#define PROJ_ELEMS (NROWS * NJ)     // 270336
#define DN (D_DIM * N_ST)           // 12288

// proj GEMM tiling
#define DSPLIT 8
#define DSEG (D_DIM / DSPLIT)       // 96
#define DK 32
#define NCHUNK (DSEG / DK)          // 3
#define RB 128
#define XST 132
#define WST 64

typedef float v2f __attribute__((ext_vector_type(2)));

__device__ __forceinline__ float fast_exp2(float x) {
#if __has_builtin(__builtin_amdgcn_exp2f)
  return __builtin_amdgcn_exp2f(x);
#else
  return __expf(x * 0.69314718055994531f);
#endif
}

// softplus = log2(1+2^(v*log2e))*ln2; guard large v (exp2 -> inf)
__device__ __forceinline__ float softplus_f(float v) {
  float e = fast_exp2(v * 1.44269504088896f);
  float l = __log2f(1.0f + e) * 0.69314718055994531f;
  return (v > 15.0f) ? v : l;
}

// pw2[k] = {e1^(2k+1), e1^(2k+2)} via log-depth tree
__device__ __forceinline__ void pow_tree2(float e1, v2f pw2[8]) {
  float e2s = e1 * e1;
  float e4s = e2s * e2s;
  float e8s = e4s * e4s;
  v2f s2 = {e2s, e2s}, s4 = {e4s, e4s}, s8 = {e8s, e8s};
  pw2[0] = (v2f){e1, e2s};
  pw2[1] = pw2[0] * s2;
  pw2[2] = pw2[0] * s4;
  pw2[3] = pw2[1] * s4;
  pw2[4] = pw2[0] * s8;
  pw2[5] = pw2[1] * s8;
  pw2[6] = pw2[2] * s8;
  pw2[7] = pw2[3] * s8;
}

// ---------------------------------------------------------------------------
// Projection GEMM, K-split 8 ways -> PBC partials. (Round-3 proven form;
// atomics epilogue was 8x worse — see round-10 post-mortem.)
// ---------------------------------------------------------------------------
__global__ __launch_bounds__(256) void k_proj_gemm(
    const float* __restrict__ x, const float* __restrict__ W_bc,
    const float* __restrict__ W_1, float* __restrict__ PBC) {
  __shared__ float xs_t[DK * XST];
  __shared__ float ws_t[DK * WST];

  const int ds  = blockIdx.x % DSPLIT;
  const int rb0 = (blockIdx.x / DSPLIT) * RB;
  const int dbase = ds * DSEG;
  const int tid = threadIdx.x;
  const int rg = tid & 31;
  const int jg = tid >> 5;

  float acc[4][5];
#pragma unroll
  for (int i = 0; i < 4; ++i)
#pragma unroll
    for (int k = 0; k < 5; ++k) acc[i][k] = 0.0f;

  const int lrow = tid >> 1;
  const int lhalf = (tid & 1) * 16;
  const float* xg_row = x + (size_t)(rb0 + lrow) * D_DIM + dbase + lhalf;

  for (int ch = 0; ch < NCHUNK; ++ch) {
    const int dc = dbase + ch * DK;
    float4 xv[4];
#pragma unroll
    for (int q = 0; q < 4; ++q)
      xv[q] = *(const float4*)(xg_row + ch * DK + q * 4);
    float wv[8];
    int widx[8];
#pragma unroll
    for (int u = 0; u < 8; ++u) {
      int idx = tid + u * 256;
      int dk = idx >> 6, slot = idx & 63;
      int wjg = slot >> 3, wk = slot & 7;
      int j = wjg + 8 * wk;
      float v = 0.0f;
      if (wk < 5) {
        if (j < 32)       v = W_bc[(size_t)j * D_DIM + dc + dk];
        else if (j == 32) v = W_1[dc + dk];
      }
      wv[u] = v; widx[u] = dk * WST + slot;
    }
    __syncthreads();
#pragma unroll
    for (int q = 0; q < 4; ++q) {
      xs_t[(lhalf + q * 4 + 0) * XST + lrow] = xv[q].x;
      xs_t[(lhalf + q * 4 + 1) * XST + lrow] = xv[q].y;
      xs_t[(lhalf + q * 4 + 2) * XST + lrow] = xv[q].z;
      xs_t[(lhalf + q * 4 + 3) * XST + lrow] = xv[q].w;
    }
#pragma unroll
    for (int u = 0; u < 8; ++u) ws_t[widx[u]] = wv[u];
    __syncthreads();
#pragma unroll 8
    for (int dk = 0; dk < DK; ++dk) {
      float4 xr = *(const float4*)&xs_t[dk * XST + rg * 4];
      float4 wr = *(const float4*)&ws_t[dk * WST + jg * 8];
      float w4  = ws_t[dk * WST + jg * 8 + 4];
      float xa[4] = {xr.x, xr.y, xr.z, xr.w};
      float wa[5] = {wr.x, wr.y, wr.z, wr.w, w4};
#pragma unroll
      for (int i = 0; i < 4; ++i)
#pragma unroll
        for (int k = 0; k < 5; ++k)
          acc[i][k] = fmaf(xa[i], wa[k], acc[i][k]);
    }
  }

  float* pb = PBC + (size_t)ds * PROJ_ELEMS;
#pragma unroll
  for (int i = 0; i < 4; ++i) {
    int row = rb0 + rg * 4 + i;
#pragma unroll
    for (int k = 0; k < 5; ++k) {
      int j = jg + 8 * k;
      if (k < 4 || jg == 0) pb[(size_t)row * NJ + j] = acc[i][k];
    }
  }
}

// Sum K-split partials + bias -> padded BC48 rows.
__global__ __launch_bounds__(256) void k_proj_reduce(
    const float* __restrict__ PBC, const float* __restrict__ b_bc,
    const float* __restrict__ b_1, float* __restrict__ BC48) {
  const int idx = blockIdx.x * 256 + threadIdx.x;   // < PROJ_ELEMS
  const int row = idx / NJ;
  const int j = idx - row * NJ;
  float s = 0.0f;
#pragma unroll
  for (int k = 0; k < DSPLIT; ++k) s += PBC[(size_t)k * PROJ_ELEMS + idx];
  s += (j < 32) ? b_bc[j] : b_1[0];
  BC48[(size_t)row * BCS + j] = s;
}

// ---------------------------------------------------------------------------
// Pass 1: per-chunk local scan, h0=0. Emits y_local -> out, chunk-end state H
// and delta-sum DS. Geometric-A fast path: dA_n = e1^(n+1).
// ---------------------------------------------------------------------------
template <int LC>
__global__ __launch_bounds__(256, 6) void k_scan1(
    const float* __restrict__ x, const float* __restrict__ A_log,
    const float* __restrict__ W_d, const float* __restrict__ b_d,
    const float* __restrict__ BC48, float* __restrict__ DS,
    float* __restrict__ H, float* __restrict__ out, int NC) {
  const int cb = blockIdx.x % 3;
  const int c  = (blockIdx.x / 3) % NC;
  const int b  = blockIdx.x / (3 * NC);
  const int d  = cb * 256 + threadIdx.x;

  const float wd = W_d[d], bd = b_d[d];
  float Aln[N_ST];
  {
    const float4* al4 = (const float4*)(A_log + (size_t)d * N_ST);
#pragma unroll
    for (int q = 0; q < 4; ++q) {
      float4 v = al4[q];
      Aln[4*q+0] = -__expf(v.x) * 1.44269504088896f;
      Aln[4*q+1] = -__expf(v.y) * 1.44269504088896f;
      Aln[4*q+2] = -__expf(v.z) * 1.44269504088896f;
      Aln[4*q+3] = -__expf(v.w) * 1.44269504088896f;
    }
  }
  bool geom = true;
#pragma unroll
  for (int n = 1; n < N_ST; ++n) {
    float ref = (float)(n + 1) * Aln[0];
    geom = geom && (fabsf(Aln[n] - ref) <= 1e-4f * fabsf(ref) + 1e-12f);
  }
  const float a0 = Aln[0];

  v2f h2[8];
#pragma unroll
  for (int k = 0; k < 8; ++k) h2[k] = (v2f){0.0f, 0.0f};
  float dsum = 0.0f;

  const int l0 = c * LC;
  const float* bc = BC48 + (size_t)(b * L_SEQ + l0) * BCS;
  const float* xp = x + (size_t)(b * L_SEQ + l0) * D_DIM + d;
  float* op = out + (size_t)(b * L_SEQ + l0) * D_DIM + d;

  if (geom) {
#pragma unroll 8
    for (int l = 0; l < LC; ++l) {
      const float* r = bc + l * BCS;
      float4 B0 = *(const float4*)(r + 0);
      float4 B1 = *(const float4*)(r + 4);
      float4 B2 = *(const float4*)(r + 8);
      float4 B3 = *(const float4*)(r + 12);
      float4 C0 = *(const float4*)(r + 16);
      float4 C1 = *(const float4*)(r + 20);
      float4 C2 = *(const float4*)(r + 24);
      float4 C3 = *(const float4*)(r + 28);
      float s1 = r[32];
      float delta = softplus_f(fmaf(s1, wd, bd));
      float xv = xp[(size_t)l * D_DIM];
      float f = delta * xv;
      dsum += delta;
      v2f pw2[8];
      pow_tree2(fast_exp2(a0 * delta), pw2);
      v2f f2 = {f, f};
      v2f y2 = {0.0f, 0.0f};
      h2[0] = pw2[0] * h2[0] + f2 * (v2f){B0.x, B0.y};  y2 += h2[0] * (v2f){C0.x, C0.y};
      h2[1] = pw2[1] * h2[1] + f2 * (v2f){B0.z, B0.w};  y2 += h2[1] * (v2f){C0.z, C0.w};
      h2[2] = pw2[2] * h2[2] + f2 * (v2f){B1.x, B1.y};  y2 += h2[2] * (v2f){C1.x, C1.y};
      h2[3] = pw2[3] * h2[3] + f2 * (v2f){B1.z, B1.w};  y2 += h2[3] * (v2f){C1.z, C1.w};
      h2[4] = pw2[4] * h2[4] + f2 * (v2f){B2.x, B2.y};  y2 += h2[4] * (v2f){C2.x, C2.y};
      h2[5] = pw2[5] * h2[5] + f2 * (v2f){B2.z, B2.w};  y2 += h2[5] * (v2f){C2.z, C2.w};
      h2[6] = pw2[6] * h2[6] + f2 * (v2f){B3.x, B3.y};  y2 += h2[6] * (v2f){C3.x, C3.y};
      h2[7] = pw2[7] * h2[7] + f2 * (v2f){B3.z, B3.w};  y2 += h2[7] * (v2f){C3.z, C3.w};
      op[(size_t)l * D_DIM] = y2.x + y2.y;
    }
  } else {
#pragma unroll 4
    for (int l = 0; l < LC; ++l) {
      const float* r = bc + l * BCS;
      float s1 = r[32];
      float delta = softplus_f(fmaf(s1, wd, bd));
      float f = delta * xp[(size_t)l * D_DIM];
      dsum += delta;
      float y = 0.0f;
#pragma unroll
      for (int k = 0; k < 8; ++k) {
        h2[k].x = fmaf(fast_exp2(delta * Aln[2*k]),   h2[k].x, f * r[2*k]);
        h2[k].y = fmaf(fast_exp2(delta * Aln[2*k+1]), h2[k].y, f * r[2*k+1]);
        y = fmaf(h2[k].x, r[16 + 2*k], y);
        y = fmaf(h2[k].y, r[16 + 2*k + 1], y);
      }
      op[(size_t)l * D_DIM] = y;
    }
  }

  DS[((size_t)b * NC + c) * D_DIM + d] = dsum;
  size_t base = ((size_t)(b * NC + c) * D_DIM + d) * N_ST;
  float4* H4 = (float4*)(H + base);
#pragma unroll
  for (int q = 0; q < 4; ++q)
    H4[q] = make_float4(h2[2*q].x, h2[2*q].y, h2[2*q+1].x, h2[2*q+1].y);
}

// ---------------------------------------------------------------------------
// Pass 2: inter-chunk combine, in-place, 8-deep prefetch. NC multiple of 8.
// ---------------------------------------------------------------------------
__global__ __launch_bounds__(256) void k_combine(
    const float* __restrict__ A_log, const float* __restrict__ DS,
    float* __restrict__ H, int NC) {
  const int b  = blockIdx.x / 48;
  const int tl = (blockIdx.x % 48) * 256 + threadIdx.x;   // 0..12287
  const int d = tl >> 4, n = tl & 15;
  const float Aln1 = -__expf(A_log[d * N_ST + n]) * 1.44269504088896f;
  const float* dsp = DS + (size_t)b * NC * D_DIM + d;
  float* Hp = H + (size_t)b * NC * DN + tl;

  float h = 0.0f;
  float pds[8], ph[8];
#pragma unroll
  for (int k = 0; k < 8; ++k) {
    pds[k] = dsp[(size_t)k * D_DIM];
    ph[k]  = Hp[(size_t)k * DN];
  }
  for (int g = 0; g < NC; g += 8) {
    float nds[8], nh[8];
    if (g + 8 < NC) {
#pragma unroll
      for (int k = 0; k < 8; ++k) {
        nds[k] = dsp[(size_t)(g + 8 + k) * D_DIM];
        nh[k]  = Hp[(size_t)(g + 8 + k) * DN];
      }
    }
#pragma unroll
    for (int k = 0; k < 8; ++k) {
      float p = fast_exp2(Aln1 * pds[k]);
      Hp[(size_t)(g + k) * DN] = h;                 // incoming state
      h = fmaf(p, h, ph[k]);
    }
#pragma unroll
    for (int k = 0; k < 8; ++k) { pds[k] = nds[k]; ph[k] = nh[k]; }
  }
}

// ---------------------------------------------------------------------------
// Pass 3: correction only. out[l] += sum_n exp(A_n * S_l) * h_in_n * C_l,n.
// Grid excludes c == 0 (already exact). No x read, no h recurrence.
// ---------------------------------------------------------------------------
template <int LC>
__global__ __launch_bounds__(256, 6) void k_scan2(
    const float* __restrict__ A_log, const float* __restrict__ W_d,
    const float* __restrict__ b_d, const float* __restrict__ BC48,
    const float* __restrict__ HIN, float* __restrict__ out, int NC) {
  const int cb  = blockIdx.x % 3;
  const int idx = blockIdx.x / 3;          // 0 .. NB*(NC-1)-1
  const int c   = idx % (NC - 1) + 1;      // chunks 1..NC-1
  const int b   = idx / (NC - 1);
  const int d   = cb * 256 + threadIdx.x;

  const float wd = W_d[d], bd = b_d[d];
  float Aln[N_ST];
  {
    const float4* al4 = (const float4*)(A_log + (size_t)d * N_ST);
#pragma unroll
    for (int q = 0; q < 4; ++q) {
      float4 v = al4[q];
      Aln[4*q+0] = -__expf(v.x) * 1.44269504088896f;
      Aln[4*q+1] = -__expf(v.y) * 1.44269504088896f;
      Aln[4*q+2] = -__expf(v.z) * 1.44269504088896f;
      Aln[4*q+3] = -__expf(v.w) * 1.44269504088896f;
    }
  }
  bool geom = true;
#pragma unroll
  for (int n = 1; n < N_ST; ++n) {
    float ref = (float)(n + 1) * Aln[0];
    geom = geom && (fabsf(Aln[n] - ref) <= 1e-4f * fabsf(ref) + 1e-12f);
  }
  const float a0 = Aln[0];

  v2f hin2[8];
  {
    size_t base = ((size_t)(b * NC + c) * D_DIM + d) * N_ST;
    const float4* HIN4 = (const float4*)(HIN + base);
#pragma unroll
    for (int q = 0; q < 4; ++q) {
      float4 v = HIN4[q];
      hin2[2*q]   = (v2f){v.x, v.y};
      hin2[2*q+1] = (v2f){v.z, v.w};
    }
  }

  const int l0 = c * LC;
  const float* bc = BC48 + (size_t)(b * L_SEQ + l0) * BCS;
  float* op = out + (size_t)(b * L_SEQ + l0) * D_DIM + d;

  if (geom) {
    float S = 0.0f;
#pragma unroll 8
    for (int l = 0; l < LC; ++l) {
      const float* r = bc + l * BCS;
      float yl = op[(size_t)l * D_DIM];            // y_local from pass 1
      float4 C0 = *(const float4*)(r + 16);
      float4 C1 = *(const float4*)(r + 20);
      float4 C2 = *(const float4*)(r + 24);
      float4 C3 = *(const float4*)(r + 28);
      float s1 = r[32];
      float delta = softplus_f(fmaf(s1, wd, bd));
      S += delta;
      v2f pw2[8];
      pow_tree2(fast_exp2(a0 * S), pw2);
      v2f acc = {0.0f, 0.0f};
      acc += pw2[0] * (hin2[0] * (v2f){C0.x, C0.y});
      acc += pw2[1] * (hin2[1] * (v2f){C0.z, C0.w});
      acc += pw2[2] * (hin2[2] * (v2f){C1.x, C1.y});
      acc += pw2[3] * (hin2[3] * (v2f){C1.z, C1.w});
      acc += pw2[4] * (hin2[4] * (v2f){C2.x, C2.y});
      acc += pw2[5] * (hin2[5] * (v2f){C2.z, C2.w});
      acc += pw2[6] * (hin2[6] * (v2f){C3.x, C3.y});
      acc += pw2[7] * (hin2[7] * (v2f){C3.z, C3.w});
      op[(size_t)l * D_DIM] = yl + acc.x + acc.y;
    }
  } else {
    float S = 0.0f;
#pragma unroll 4
    for (int l = 0; l < LC; ++l) {
      const float* r = bc + l * BCS;
      float yl = op[(size_t)l * D_DIM];
      float s1 = r[32];
      float delta = softplus_f(fmaf(s1, wd, bd));
      S += delta;
      float corr = 0.0f;
#pragma unroll
      for (int k = 0; k < 8; ++k) {
        corr = fmaf(fast_exp2(Aln[2*k]   * S) * hin2[k].x, r[16 + 2*k],     corr);
        corr = fmaf(fast_exp2(Aln[2*k+1] * S) * hin2[k].y, r[16 + 2*k + 1], corr);
      }
      op[(size_t)l * D_DIM] = yl + corr;
    }
  }
}

// ---------------------------------------------------------------------------
extern "C" void kernel_launch(void* const* d_in, const int* in_sizes, int n_in,
                              void* d_out, int out_size, void* d_ws, size_t ws_size,
                              hipStream_t stream) {
  const float* x     = (const float*)d_in[0];
  const float* A_log = (const float*)d_in[1];
  const float* W_bc  = (const float*)d_in[2];
  const float* b_bc  = (const float*)d_in[3];
  const float* W_1   = (const float*)d_in[4];
  const float* b_1   = (const float*)d_in[5];
  const float* W_d   = (const float*)d_in[6];
  const float* b_d   = (const float*)d_in[7];
  float* out = (float*)d_out;
  float* ws  = (float*)d_ws;

  // ws (floats): BC48 393216 + PBC 8*270336 + DS 3072*NC + H 49152*NC
  int NC = 64;
  {
    size_t need = ((size_t)NROWS * BCS + 8ull * PROJ_ELEMS +
                   (3072ull + 49152ull) * 64) * 4ull;
    if (ws_size < need) NC = 32;
  }

  float* BC48 = ws;
  float* PBC  = ws + (size_t)NROWS * BCS;
  float* DSb  = PBC + (size_t)DSPLIT * PROJ_ELEMS;
  float* H    = DSb + (size_t)3072 * NC;

  k_proj_gemm<<<(NROWS / RB) * DSPLIT, 256, 0, stream>>>(x, W_bc, W_1, PBC);
  k_proj_reduce<<<(PROJ_ELEMS + 255) / 256, 256, 0, stream>>>(PBC, b_bc, b_1, BC48);

  const int gs1 = 3 * NB * NC;
  const int gs2 = 3 * NB * (NC - 1);
  if (NC == 64) {
    k_scan1<32><<<gs1, 256, 0, stream>>>(x, A_log, W_d, b_d, BC48, DSb, H, out, NC);
    k_combine<<<192, 256, 0, stream>>>(A_log, DSb, H, NC);
    k_scan2<32><<<gs2, 256, 0, stream>>>(A_log, W_d, b_d, BC48, H, out, NC);
  } else {
    k_scan1<64><<<gs1, 256, 0, stream>>>(x, A_log, W_d, b_d, BC48, DSb, H, out, NC);
    k_combine<<<192, 256, 0, stream>>>(A_log, DSb, H, NC);
    k_scan2<64><<<gs2, 256, 0, stream>>>(A_log, W_d, b_d, BC48, H, out, NC);
  }
}